// Round 2
// baseline (287.194 us; speedup 1.0000x reference)
//
#include <hip/hip_runtime.h>

typedef unsigned short u16;
typedef unsigned int   u32;
typedef __attribute__((ext_vector_type(8)))  __bf16 bf16x8;
typedef __attribute__((ext_vector_type(4)))  float  f32x4;
typedef __attribute__((ext_vector_type(16))) float  f32x16;
typedef __attribute__((ext_vector_type(4)))  float  fl4;
typedef __attribute__((ext_vector_type(4)))  u16    u16x4;
typedef __attribute__((ext_vector_type(4)))  u32    u32x4;

#define NB 16
#define NT 2048
#define NC 1024
#define ND 128

__device__ __forceinline__ u16 f2bf(float f) {
  u32 u = __builtin_bit_cast(u32, f);
  u = (u + 0x7fffu + ((u >> 16) & 1u)) >> 16;
  return (u16)u;
}

__device__ __forceinline__ u32 pk2(float lo, float hi) {
  return (u32)f2bf(lo) | ((u32)f2bf(hi) << 16);
}

// -------------------- Kernel 1: QKV projection --------------------
// Y[32768,128] = X[32768,1024] @ W[1024,128], bf16 MFMA 16x16x32.
// kind 0 -> q (scaled by log2e/sqrt(128)), 1 -> k, 2 -> v stored transposed [B][D][T].
__global__ __launch_bounds__(256) void qkv_proj_k(
    const float* __restrict__ x, const float* __restrict__ Wq,
    const float* __restrict__ Wk, const float* __restrict__ Wv,
    u16* __restrict__ qo, u16* __restrict__ ko, u16* __restrict__ vto)
{
  const int kind = blockIdx.x;          // 0..2  (fastest -> x-tile shared in L2/L3)
  const int tile = blockIdx.y;          // 0..255
  const float* __restrict__ W = (kind == 0) ? Wq : (kind == 1) ? Wk : Wv;
  const int tid  = threadIdx.x;
  const int lane = tid & 63;
  const int wid  = tid >> 6;
  const int wr = wid >> 1, wc = wid & 1;
  const int l15 = lane & 15, l4 = lane >> 4;
  const int m0 = tile * 128;

  __shared__ u16 Xs[128][72];
  __shared__ u16 Ws[128][72];

  f32x4 acc[4][4] = {};

  for (int k0 = 0; k0 < NC; k0 += 64) {
    __syncthreads();
    #pragma unroll
    for (int it = 0; it < 8; ++it) {
      int row = it * 16 + (tid >> 4);
      int c4  = (tid & 15) * 4;
      fl4 xv = *(const fl4*)(x + (size_t)(m0 + row) * NC + k0 + c4);
      u16x4 pk;
      pk[0] = f2bf(xv[0]); pk[1] = f2bf(xv[1]); pk[2] = f2bf(xv[2]); pk[3] = f2bf(xv[3]);
      *(u16x4*)&Xs[row][c4] = pk;
    }
    #pragma unroll
    for (int it = 0; it < 8; ++it) {
      int kk = it * 8 + (tid >> 5);
      int n4 = (tid & 31) * 4;
      fl4 wv = *(const fl4*)(W + (size_t)(k0 + kk) * ND + n4);
      Ws[n4 + 0][kk] = f2bf(wv[0]);
      Ws[n4 + 1][kk] = f2bf(wv[1]);
      Ws[n4 + 2][kk] = f2bf(wv[2]);
      Ws[n4 + 3][kk] = f2bf(wv[3]);
    }
    __syncthreads();
    #pragma unroll
    for (int ks = 0; ks < 2; ++ks) {
      bf16x8 a[4], b[4];
      #pragma unroll
      for (int f = 0; f < 4; ++f) {
        a[f] = *(const bf16x8*)&Xs[wr * 64 + f * 16 + l15][ks * 32 + l4 * 8];
        b[f] = *(const bf16x8*)&Ws[wc * 64 + f * 16 + l15][ks * 32 + l4 * 8];
      }
      #pragma unroll
      for (int fm = 0; fm < 4; ++fm)
        #pragma unroll
        for (int fn = 0; fn < 4; ++fn)
          acc[fm][fn] = __builtin_amdgcn_mfma_f32_16x16x32_bf16(a[fm], b[fn], acc[fm][fn], 0, 0, 0);
    }
  }

  if (kind < 2) {
    u16* __restrict__ o = (kind == 0) ? qo : ko;
    const float sc = (kind == 0) ? 0.12752539240377073f : 1.0f; // log2e/sqrt(128)
    #pragma unroll
    for (int fm = 0; fm < 4; ++fm)
      #pragma unroll
      for (int fn = 0; fn < 4; ++fn) {
        int col = wc * 64 + fn * 16 + l15;
        #pragma unroll
        for (int r = 0; r < 4; ++r) {
          int row = m0 + wr * 64 + fm * 16 + l4 * 4 + r;
          o[(size_t)row * ND + col] = f2bf(acc[fm][fn][r] * sc);
        }
      }
  } else {
    #pragma unroll
    for (int fm = 0; fm < 4; ++fm)
      #pragma unroll
      for (int fn = 0; fn < 4; ++fn) {
        int col = wc * 64 + fn * 16 + l15;            // d
        int m   = m0 + wr * 64 + fm * 16 + l4 * 4;    // flat row, 4 consecutive t
        int bb = m >> 11, t0 = m & (NT - 1);
        u16x4 pk;
        #pragma unroll
        for (int r = 0; r < 4; ++r) pk[r] = f2bf(acc[fm][fn][r]);
        *(u16x4*)(vto + ((size_t)bb * ND + col) * NT + t0) = pk;
      }
  }
}

// -------------------- Kernel 2: flash attention --------------------
// One wave = one (batch, 32-row q-tile). Swapped QK^T (mfma(K,Q)) so each
// lane owns one q-row of S^T; softmax in-register; all cross-lane movement
// via __shfl_xor(·,32) partner exchange (direction-proof).
__global__ __launch_bounds__(256, 1) void attn_fwd_k(
    const u16* __restrict__ qw, const u16* __restrict__ kw,
    const u16* __restrict__ vtw, float* __restrict__ out)
{
  const int tid  = threadIdx.x;
  const int lane = tid & 63;
  const int wid  = tid >> 6;
  const int l31  = lane & 31;
  const int hi   = lane >> 5;

  // balanced heavy+light pairing over 1024 wave-tasks
  int pairIdx = blockIdx.x * 2 + (wid >> 1);          // 0..511
  int rho = (wid & 1) ? (1023 - pairIdx) : pairIdx;   // task rank
  int bb = rho & 15;
  int qi = 63 - (rho >> 4);                           // q-tile, heavy ranks first
  int q0 = qi * 32;
  int qrow = q0 + l31;

  const u16* __restrict__ qb = qw  + (size_t)bb * NT * ND;
  const u16* __restrict__ kb = kw  + (size_t)bb * NT * ND;
  const u16* __restrict__ vb = vtw + (size_t)bb * ND * NT;

  // Q fragments (B-operand): lane holds Q[q0+l31][s*16 + hi*8 + 0..7]
  bf16x8 qf[8];
  #pragma unroll
  for (int s = 0; s < 8; ++s)
    qf[s] = *(const bf16x8*)(qb + (size_t)qrow * ND + s * 16 + hi * 8);

  f32x16 of[4] = {};
  float m_run = -__builtin_inff();
  float l_run = 0.f;

  const int nsteps = (qi >> 1) + 1;
  for (int s = 0; s < nsteps; ++s) {
    const int kv0 = s * 64;
    const bool masked = (s == nsteps - 1);

    // K fragments (A-operand), both 32-row kv sub-tiles
    bf16x8 kf0[8], kf1[8];
    #pragma unroll
    for (int t = 0; t < 8; ++t) {
      kf0[t] = *(const bf16x8*)(kb + (size_t)(kv0 + l31) * ND + t * 16 + hi * 8);
      kf1[t] = *(const bf16x8*)(kb + (size_t)(kv0 + 32 + l31) * ND + t * 16 + hi * 8);
    }
    f32x16 st0 = {}, st1 = {};
    #pragma unroll
    for (int t = 0; t < 8; ++t) {
      st0 = __builtin_amdgcn_mfma_f32_32x32x16_bf16(kf0[t], qf[t], st0, 0, 0, 0);
      st1 = __builtin_amdgcn_mfma_f32_32x32x16_bf16(kf1[t], qf[t], st1, 0, 0, 0);
    }
    // V^T fragments issued early so latency hides under softmax
    bf16x8 vf[4][4];
    #pragma unroll
    for (int dt = 0; dt < 4; ++dt)
      #pragma unroll
      for (int ks = 0; ks < 4; ++ks)
        vf[dt][ks] = *(const bf16x8*)(vb + (size_t)(dt * 32 + l31) * NT + kv0 + ks * 16 + hi * 8);

    if (masked) {
      #pragma unroll
      for (int r = 0; r < 16; ++r) {
        int crow = (r & 3) + 8 * (r >> 2) + 4 * hi;
        st0[r] = (kv0 + crow      <= qrow) ? st0[r] : -1e30f;
        st1[r] = (kv0 + 32 + crow <= qrow) ? st1[r] : -1e30f;
      }
    }

    // row max: 32 in-lane values + partner half via shfl_xor
    float pmax = -1e30f;
    #pragma unroll
    for (int r = 0; r < 16; ++r) pmax = fmaxf(pmax, fmaxf(st0[r], st1[r]));
    pmax = fmaxf(pmax, __shfl_xor(pmax, 32, 64));

    const bool no_rescale = (pmax <= m_run);
    const float m_new = fmaxf(m_run, pmax);
    const float fac = __builtin_amdgcn_exp2f(m_run - m_new);
    float rsum = 0.f;
    #pragma unroll
    for (int r = 0; r < 16; ++r) {
      st0[r] = __builtin_amdgcn_exp2f(st0[r] - m_new);
      st1[r] = __builtin_amdgcn_exp2f(st1[r] - m_new);
      rsum += st0[r] + st1[r];
    }
    rsum += __shfl_xor(rsum, 32, 64);
    l_run = l_run * fac + rsum;
    m_run = m_new;

    if (!__all(no_rescale)) {
      #pragma unroll
      for (int r = 0; r < 16; ++r) {
        float fr = __shfl(fac, (r & 3) + 8 * (r >> 2) + 4 * hi, 64);
        #pragma unroll
        for (int dt = 0; dt < 4; ++dt) of[dt][r] *= fr;
      }
    }

    // P (f32, D-layout) -> bf16 A-operand fragments.
    // Group g covers kv [g*16, g*16+16); source regs: g0=st0[0..7], g1=st0[8..15],
    // g2=st1[0..7], g3=st1[8..15].  Within a group, own lane holds
    // kv g*16 + {0..3}+4hi and {8..11}+4hi; partner holds the complement.
    // Target A-layout: lane needs kv g*16 + hi*8 + (0..7).
    u32x4 pa[4];
    #pragma unroll
    for (int g = 0; g < 4; ++g) {
      const float* sp = (g < 2) ? (const float*)&st0 : (const float*)&st1;
      const int o8 = (g & 1) * 8;
      u32 a0 = pk2(sp[o8 + 0], sp[o8 + 1]);   // hi=0: kv+0,1   hi=1: kv+4,5
      u32 a1 = pk2(sp[o8 + 2], sp[o8 + 3]);   // hi=0: kv+2,3   hi=1: kv+6,7
      u32 b0 = pk2(sp[o8 + 4], sp[o8 + 5]);   // hi=0: kv+8,9   hi=1: kv+12,13
      u32 b1 = pk2(sp[o8 + 6], sp[o8 + 7]);   // hi=0: kv+10,11 hi=1: kv+14,15
      u32 ta0 = __shfl_xor(a0, 32, 64);
      u32 ta1 = __shfl_xor(a1, 32, 64);
      u32 tb0 = __shfl_xor(b0, 32, 64);
      u32 tb1 = __shfl_xor(b1, 32, 64);
      pa[g][0] = hi ? tb0 : a0;   // kv+0,1  (hi=0) | kv+8,9   (hi=1)
      pa[g][1] = hi ? tb1 : a1;   // kv+2,3          | kv+10,11
      pa[g][2] = hi ? b0  : ta0;  // kv+4,5          | kv+12,13
      pa[g][3] = hi ? b1  : ta1;  // kv+6,7          | kv+14,15
    }

    #pragma unroll
    for (int ks = 0; ks < 4; ++ks) {
      bf16x8 paf = __builtin_bit_cast(bf16x8, pa[ks]);
      #pragma unroll
      for (int dt = 0; dt < 4; ++dt)
        of[dt] = __builtin_amdgcn_mfma_f32_32x32x16_bf16(paf, vf[dt][ks], of[dt], 0, 0, 0);
    }
  }

  const float rl = 1.0f / l_run;
  #pragma unroll
  for (int r = 0; r < 16; ++r) {
    int crow = (r & 3) + 8 * (r >> 2) + 4 * hi;
    float lr = __shfl(rl, crow, 64);
    #pragma unroll
    for (int dt = 0; dt < 4; ++dt)
      out[((size_t)(bb * NT + q0 + crow)) * ND + dt * 32 + l31] = of[dt][r] * lr;
  }
}

extern "C" void kernel_launch(void* const* d_in, const int* in_sizes, int n_in,
                              void* d_out, int out_size, void* d_ws, size_t ws_size,
                              hipStream_t stream) {
  (void)in_sizes; (void)n_in; (void)out_size; (void)ws_size;
  const float* x  = (const float*)d_in[0];
  const float* Wq = (const float*)d_in[1];
  const float* Wk = (const float*)d_in[2];
  const float* Wv = (const float*)d_in[3];
  float* out = (float*)d_out;

  u16* qws  = (u16*)d_ws;                               // [B][T][D] bf16
  u16* kws  = qws + (size_t)NB * NT * ND;               // [B][T][D] bf16
  u16* vtws = kws + (size_t)NB * NT * ND;               // [B][D][T] bf16

  qkv_proj_k<<<dim3(3, 256), dim3(256), 0, stream>>>(x, Wq, Wk, Wv, qws, kws, vtws);
  attn_fwd_k<<<dim3(256), dim3(256), 0, stream>>>(qws, kws, vtws, out);
}

// Round 3
// 168.153 us; speedup vs baseline: 1.7079x; 1.7079x over previous
//
#include <hip/hip_runtime.h>

typedef unsigned short u16;
typedef unsigned int   u32;
typedef __attribute__((ext_vector_type(8)))  __bf16 bf16x8;
typedef __attribute__((ext_vector_type(4)))  float  f32x4;
typedef __attribute__((ext_vector_type(16))) float  f32x16;
typedef __attribute__((ext_vector_type(4)))  float  fl4;
typedef __attribute__((ext_vector_type(4)))  u16    u16x4;
typedef __attribute__((ext_vector_type(4)))  u32    u32x4;

#define NB 16
#define NT 2048
#define NC 1024
#define ND 128

__device__ __forceinline__ u16 f2bf(float f) {
  u32 u = __builtin_bit_cast(u32, f);
  u = (u + 0x7fffu + ((u >> 16) & 1u)) >> 16;
  return (u16)u;
}

__device__ __forceinline__ u32 pk2(float lo, float hi) {
  return (u32)f2bf(lo) | ((u32)f2bf(hi) << 16);
}

// -------------------- Kernel 0: W transpose prep --------------------
// Wt[kind][n][k] = W_kind[k][n] as bf16.  768 KB total, L2-resident after.
__global__ __launch_bounds__(256) void wprep_k(
    const float* __restrict__ Wq, const float* __restrict__ Wk,
    const float* __restrict__ Wv, u16* __restrict__ wt)
{
  const int kind = blockIdx.x;
  const int nb   = blockIdx.y;          // 0..7
  const float* __restrict__ W = (kind == 0) ? Wq : (kind == 1) ? Wk : Wv;
  const int t = threadIdx.x;
  const int n  = nb * 16 + (t >> 4);
  const int k0 = (t & 15) * 64;
  u16* __restrict__ o = wt + ((size_t)kind * ND + n) * NC + k0;
  #pragma unroll 4
  for (int i = 0; i < 16; ++i) {
    u16x4 pk;
    #pragma unroll
    for (int j = 0; j < 4; ++j)
      pk[j] = f2bf(W[(size_t)(k0 + i * 4 + j) * ND + n]);
    *(u16x4*)(o + i * 4) = pk;
  }
}

// -------------------- Kernel 1: QKV projection --------------------
// Y[32768,128] = X[32768,1024] @ W[1024,128], bf16 MFMA 32x32x16.
// X staged in LDS (XOR-swizzled); B-fragments direct from global Wt (L2-hit).
// kind 0 -> q (scaled by log2e/sqrt(128)), 1 -> k, 2 -> v stored transposed [B][D][T].
__global__ __launch_bounds__(256) void qkv_proj_k(
    const float* __restrict__ x, const u16* __restrict__ wt,
    u16* __restrict__ qo, u16* __restrict__ ko, u16* __restrict__ vto)
{
  const int kind = blockIdx.x;          // fastest -> 3 kinds share x-tile in L2
  const int tile = blockIdx.y;          // 0..255
  const int tid  = threadIdx.x;
  const int lane = tid & 63;
  const int wid  = tid >> 6;
  const int wr = wid >> 1, wc = wid & 1;
  const int l31 = lane & 31, hi = lane >> 5;
  const int m0 = tile * 128;

  __shared__ u16 Xs[128 * 64];          // byte = row*128 + (col2 ^ ((row&7)<<4))
  char* const xsb = (char*)Xs;

  const u16* __restrict__ wkind = wt + (size_t)kind * ND * NC;

  f32x16 acc[2][2] = {};

  // staging coords (fixed per thread)
  const int srow = tid >> 4;            // + it*16
  const int sc4  = (tid & 15) * 4;      // f32 col
  // A-frag read swizzle depends only on lane (row ≡ l31 mod 8)
  const int aswz = (l31 & 7) << 4;

  for (int k0 = 0; k0 < NC; k0 += 64) {
    // B fragments for the whole 64-K chunk: global, L1/L2-resident
    bf16x8 bfr[4][2];
    #pragma unroll
    for (int ks = 0; ks < 4; ++ks)
      #pragma unroll
      for (int fn = 0; fn < 2; ++fn)
        bfr[ks][fn] = *(const bf16x8*)(wkind + (size_t)(wc * 64 + fn * 32 + l31) * NC
                                       + k0 + ks * 16 + hi * 8);
    __syncthreads();
    #pragma unroll
    for (int it = 0; it < 8; ++it) {
      int row = it * 16 + srow;
      fl4 xv = *(const fl4*)(x + (size_t)(m0 + row) * NC + k0 + sc4);
      u16x4 pk;
      pk[0] = f2bf(xv[0]); pk[1] = f2bf(xv[1]); pk[2] = f2bf(xv[2]); pk[3] = f2bf(xv[3]);
      *(u16x4*)(xsb + row * 128 + ((sc4 * 2) ^ ((row & 7) << 4))) = pk;
    }
    __syncthreads();
    #pragma unroll
    for (int ks = 0; ks < 4; ++ks) {
      bf16x8 a[2];
      #pragma unroll
      for (int fm = 0; fm < 2; ++fm) {
        int row = wr * 64 + fm * 32 + l31;
        a[fm] = *(const bf16x8*)(xsb + row * 128 + ((ks * 32 + hi * 16) ^ aswz));
      }
      #pragma unroll
      for (int fm = 0; fm < 2; ++fm)
        #pragma unroll
        for (int fn = 0; fn < 2; ++fn)
          acc[fm][fn] = __builtin_amdgcn_mfma_f32_32x32x16_bf16(a[fm], bfr[ks][fn], acc[fm][fn], 0, 0, 0);
    }
  }

  if (kind < 2) {
    u16* __restrict__ o = (kind == 0) ? qo : ko;
    const float sc = (kind == 0) ? 0.12752539240377073f : 1.0f; // log2e/sqrt(128)
    #pragma unroll
    for (int fm = 0; fm < 2; ++fm)
      #pragma unroll
      for (int fn = 0; fn < 2; ++fn) {
        int col = wc * 64 + fn * 32 + l31;
        #pragma unroll
        for (int r = 0; r < 16; ++r) {
          int row = m0 + wr * 64 + fm * 32 + (r & 3) + 8 * (r >> 2) + 4 * hi;
          o[(size_t)row * ND + col] = f2bf(acc[fm][fn][r] * sc);
        }
      }
  } else {
    #pragma unroll
    for (int fm = 0; fm < 2; ++fm)
      #pragma unroll
      for (int fn = 0; fn < 2; ++fn) {
        int col = wc * 64 + fn * 32 + l31;            // d
        int m   = m0 + wr * 64 + fm * 32;             // flat row base
        int bb = m >> 11;
        #pragma unroll
        for (int g = 0; g < 4; ++g) {
          int t0 = (m & (NT - 1)) + 8 * g + 4 * hi;   // 4 consecutive t
          u16x4 pk;
          #pragma unroll
          for (int j = 0; j < 4; ++j) pk[j] = f2bf(acc[fm][fn][g * 4 + j]);
          *(u16x4*)(vto + ((size_t)bb * ND + col) * NT + t0) = pk;
        }
      }
  }
}

// -------------------- Kernel 2: flash attention --------------------
// One wave = one (batch, 32-row q-tile). Swapped QK^T (mfma(K,Q)) so each
// lane owns one q-row of S^T; softmax in-register; all cross-lane movement
// via __shfl_xor(·,32) partner exchange (direction-proof).
__global__ __launch_bounds__(256, 1) void attn_fwd_k(
    const u16* __restrict__ qw, const u16* __restrict__ kw,
    const u16* __restrict__ vtw, float* __restrict__ out)
{
  const int tid  = threadIdx.x;
  const int lane = tid & 63;
  const int wid  = tid >> 6;
  const int l31  = lane & 31;
  const int hi   = lane >> 5;

  // balanced heavy+light pairing over 1024 wave-tasks
  int pairIdx = blockIdx.x * 2 + (wid >> 1);          // 0..511
  int rho = (wid & 1) ? (1023 - pairIdx) : pairIdx;   // task rank
  int bb = rho & 15;
  int qi = 63 - (rho >> 4);                           // q-tile, heavy ranks first
  int q0 = qi * 32;
  int qrow = q0 + l31;

  const u16* __restrict__ qb = qw  + (size_t)bb * NT * ND;
  const u16* __restrict__ kb = kw  + (size_t)bb * NT * ND;
  const u16* __restrict__ vb = vtw + (size_t)bb * ND * NT;

  // Q fragments (B-operand): lane holds Q[q0+l31][s*16 + hi*8 + 0..7]
  bf16x8 qf[8];
  #pragma unroll
  for (int s = 0; s < 8; ++s)
    qf[s] = *(const bf16x8*)(qb + (size_t)qrow * ND + s * 16 + hi * 8);

  f32x16 of[4] = {};
  float m_run = -__builtin_inff();
  float l_run = 0.f;

  const int nsteps = (qi >> 1) + 1;
  for (int s = 0; s < nsteps; ++s) {
    const int kv0 = s * 64;
    const bool masked = (s == nsteps - 1);

    // K fragments (A-operand), both 32-row kv sub-tiles
    bf16x8 kf0[8], kf1[8];
    #pragma unroll
    for (int t = 0; t < 8; ++t) {
      kf0[t] = *(const bf16x8*)(kb + (size_t)(kv0 + l31) * ND + t * 16 + hi * 8);
      kf1[t] = *(const bf16x8*)(kb + (size_t)(kv0 + 32 + l31) * ND + t * 16 + hi * 8);
    }
    f32x16 st0 = {}, st1 = {};
    #pragma unroll
    for (int t = 0; t < 8; ++t) {
      st0 = __builtin_amdgcn_mfma_f32_32x32x16_bf16(kf0[t], qf[t], st0, 0, 0, 0);
      st1 = __builtin_amdgcn_mfma_f32_32x32x16_bf16(kf1[t], qf[t], st1, 0, 0, 0);
    }
    // V^T fragments issued early so latency hides under softmax
    bf16x8 vf[4][4];
    #pragma unroll
    for (int dt = 0; dt < 4; ++dt)
      #pragma unroll
      for (int ks = 0; ks < 4; ++ks)
        vf[dt][ks] = *(const bf16x8*)(vb + (size_t)(dt * 32 + l31) * NT + kv0 + ks * 16 + hi * 8);

    if (masked) {
      #pragma unroll
      for (int r = 0; r < 16; ++r) {
        int crow = (r & 3) + 8 * (r >> 2) + 4 * hi;
        st0[r] = (kv0 + crow      <= qrow) ? st0[r] : -1e30f;
        st1[r] = (kv0 + 32 + crow <= qrow) ? st1[r] : -1e30f;
      }
    }

    // row max: 32 in-lane values + partner half via shfl_xor
    float pmax = -1e30f;
    #pragma unroll
    for (int r = 0; r < 16; ++r) pmax = fmaxf(pmax, fmaxf(st0[r], st1[r]));
    pmax = fmaxf(pmax, __shfl_xor(pmax, 32, 64));

    const bool no_rescale = (pmax <= m_run);
    const float m_new = fmaxf(m_run, pmax);
    const float fac = __builtin_amdgcn_exp2f(m_run - m_new);
    float rsum = 0.f;
    #pragma unroll
    for (int r = 0; r < 16; ++r) {
      st0[r] = __builtin_amdgcn_exp2f(st0[r] - m_new);
      st1[r] = __builtin_amdgcn_exp2f(st1[r] - m_new);
      rsum += st0[r] + st1[r];
    }
    rsum += __shfl_xor(rsum, 32, 64);
    l_run = l_run * fac + rsum;
    m_run = m_new;

    if (!__all(no_rescale)) {
      #pragma unroll
      for (int r = 0; r < 16; ++r) {
        float fr = __shfl(fac, (r & 3) + 8 * (r >> 2) + 4 * hi, 64);
        #pragma unroll
        for (int dt = 0; dt < 4; ++dt) of[dt][r] *= fr;
      }
    }

    // P (f32, D-layout) -> bf16 A-operand fragments.
    u32x4 pa[4];
    #pragma unroll
    for (int g = 0; g < 4; ++g) {
      const float* sp = (g < 2) ? (const float*)&st0 : (const float*)&st1;
      const int o8 = (g & 1) * 8;
      u32 a0 = pk2(sp[o8 + 0], sp[o8 + 1]);
      u32 a1 = pk2(sp[o8 + 2], sp[o8 + 3]);
      u32 b0 = pk2(sp[o8 + 4], sp[o8 + 5]);
      u32 b1 = pk2(sp[o8 + 6], sp[o8 + 7]);
      u32 ta0 = __shfl_xor(a0, 32, 64);
      u32 ta1 = __shfl_xor(a1, 32, 64);
      u32 tb0 = __shfl_xor(b0, 32, 64);
      u32 tb1 = __shfl_xor(b1, 32, 64);
      pa[g][0] = hi ? tb0 : a0;
      pa[g][1] = hi ? tb1 : a1;
      pa[g][2] = hi ? b0  : ta0;
      pa[g][3] = hi ? b1  : ta1;
    }

    #pragma unroll
    for (int ks = 0; ks < 4; ++ks) {
      bf16x8 paf = __builtin_bit_cast(bf16x8, pa[ks]);
      #pragma unroll
      for (int dt = 0; dt < 4; ++dt)
        of[dt] = __builtin_amdgcn_mfma_f32_32x32x16_bf16(paf, vf[dt][ks], of[dt], 0, 0, 0);
    }
  }

  const float rl = 1.0f / l_run;
  #pragma unroll
  for (int r = 0; r < 16; ++r) {
    int crow = (r & 3) + 8 * (r >> 2) + 4 * hi;
    float lr = __shfl(rl, crow, 64);
    #pragma unroll
    for (int dt = 0; dt < 4; ++dt)
      out[((size_t)(bb * NT + q0 + crow)) * ND + dt * 32 + l31] = of[dt][r] * lr;
  }
}

extern "C" void kernel_launch(void* const* d_in, const int* in_sizes, int n_in,
                              void* d_out, int out_size, void* d_ws, size_t ws_size,
                              hipStream_t stream) {
  (void)in_sizes; (void)n_in; (void)out_size; (void)ws_size;
  const float* x  = (const float*)d_in[0];
  const float* Wq = (const float*)d_in[1];
  const float* Wk = (const float*)d_in[2];
  const float* Wv = (const float*)d_in[3];
  float* out = (float*)d_out;

  u16* qws  = (u16*)d_ws;                               // [B][T][D] bf16
  u16* kws  = qws + (size_t)NB * NT * ND;               // [B][T][D] bf16
  u16* vtws = kws + (size_t)NB * NT * ND;               // [B][D][T] bf16
  u16* wtws = vtws + (size_t)NB * ND * NT;              // [3][128][1024] bf16

  wprep_k<<<dim3(3, 8), dim3(256), 0, stream>>>(Wq, Wk, Wv, wtws);
  qkv_proj_k<<<dim3(3, 256), dim3(256), 0, stream>>>(x, wtws, qws, kws, vtws);
  attn_fwd_k<<<dim3(256), dim3(256), 0, stream>>>(qws, kws, vtws, out);
}